// Round 5
// baseline (848.600 us; speedup 1.0000x reference)
//
#include <hip/hip_runtime.h>
#include <stdint.h>

typedef __attribute__((ext_vector_type(8))) short short8;
typedef __attribute__((ext_vector_type(8))) unsigned short ushort8_t;
typedef __attribute__((ext_vector_type(4))) float floatx4;

#define T1 127
#define ENC 256
#define HD 256

// workspace offsets (bytes)
#define D0_OFF    1048576u      // 512*128 u64 = 524288  (epoch-tagged d words)
#define D1_OFF    1572864u
#define WEFF_OFF  2097152u      // 256 floats
#define CF_OFF    2361344u      // 512 floats (ctx·W_final[256:512] per batch)
#define DT_OFF    2885632u      // 512*256 fp32 = 524288

__device__ __forceinline__ void split_bf16(float x, unsigned& hi, unsigned& lo) {
    unsigned u = __float_as_uint(x);
    hi = u >> 16;
    float hf = __uint_as_float(hi << 16);
    float r = x - hf;
    unsigned ur = __float_as_uint(r);
    lo = (ur + 0x7fffu + ((ur >> 16) & 1u)) >> 16;
}

__device__ __forceinline__ float sigm_f(float x) { return 1.f / (1.f + __expf(-x)); }
__device__ __forceinline__ float tanh_f(float x) {
    x = fminf(9.f, fmaxf(-9.f, x));
    float e = __expf(2.f * x);
    return (e - 1.f) / (e + 1.f);
}

// One 64-B line sample, agent-coherent (sc0 sc1: bypass L1+L2, served at IC/HBM).
__device__ __forceinline__ void load64_ag(const unsigned long long* p,
                                          uint4& a, uint4& b, uint4& c, uint4& d) {
    asm volatile("global_load_dwordx4 %0, %4, off sc0 sc1\n\t"
                 "global_load_dwordx4 %1, %4, off offset:16 sc0 sc1\n\t"
                 "global_load_dwordx4 %2, %4, off offset:32 sc0 sc1\n\t"
                 "global_load_dwordx4 %3, %4, off offset:48 sc0 sc1\n\t"
                 "s_waitcnt vmcnt(0)"
                 : "=v"(a), "=v"(b), "=v"(c), "=v"(d)
                 : "v"((unsigned long long)p)
                 : "memory");
}

// ---------------- k_prep: D-buffer zero + weff collapse (W split moved inline) ----------------
__global__ __launch_bounds__(256) void k_prep(const float* __restrict__ W1,
                                              const float* __restrict__ W2,
                                              char* __restrict__ ws) {
    const int tid = threadIdx.x, bid = blockIdx.x;
    {
        const int idx = bid * 256 + tid;
        if (idx < 32768) ((uint4*)(ws + D0_OFF))[idx] = make_uint4(0, 0, 0, 0);
    }
    if (bid == 0) {
        float acc = 0.f;
        for (int j = 0; j < 128; ++j)
            acc = fmaf(W2[j], W1[j * 768 + 512 + tid], acc);
        ((float*)(ws + WEFF_OFF))[tid] = acc;
    }
}

// ---------------- k_lstm: fused attention pre-phase + persistent sequential LSTM ----------------
// R15: k_attn folded in. Identities used:
//   score[b,t] = X[b,t,:]·weff (+const shift, softmax-invariant — proven baseline trick)
//   u(b)  = W_fc[0:256]·ctx(b)  = (Σ_t e[t]·xw[b,t]) / Σ_t e[t],  xw = X[b,t,:]·W_fc[0:256]
//   cf(b) = W_final[256:]·ctx(b) = (Σ_t e[t]·xf[b,t]) / Σ_t e[t], xf = X[b,t,:]·W_final[256:]
// -> context is never materialized; X is read ONCE. Each block computes its own 16
// batches (8x redundant across hj; X = 67 MB fits IC so 7/8 reads are IC hits).
// W_hh hi/lo split now inline at fragment load. The t-loop protocol is byte-identical
// to the proven 410 us kernel; only ytv = u + wy*y_prev[.] (L1-cached load) changed.
__global__ __launch_bounds__(256, 1) void k_lstm(const float* __restrict__ W_ih,
                                                 const float* __restrict__ b_ih,
                                                 const float* __restrict__ b_hh,
                                                 const float* __restrict__ W_hh,
                                                 const float* __restrict__ X,
                                                 const float* __restrict__ y_prev,
                                                 const float* __restrict__ W_fc,
                                                 const float* __restrict__ b_fc,
                                                 const float* __restrict__ W_final,
                                                 char* __restrict__ ws) {
    __shared__ __align__(16) ushort ldh[16 * 264];
    __shared__ __align__(16) ushort ldl[16 * 264];
    __shared__ float gbuf[16 * 132];
    __shared__ float s_sc[16 * 128];
    __shared__ float s_xw[16 * 128];
    __shared__ float s_xf[16 * 128];
    __shared__ float s_u[16];

    const int tid = threadIdx.x, bid = blockIdx.x;
    const int gi = bid >> 3, hj = bid & 7;
    const int w = tid >> 6, lane = tid & 63;
    const int n16 = lane & 15, q = lane >> 4;

    unsigned long long* Dbuf0 = (unsigned long long*)(ws + D0_OFF);
    unsigned long long* Dbuf1 = (unsigned long long*)(ws + D1_OFF);
    float* dT = (float*)(ws + DT_OFF);
    float* cf = (float*)(ws + CF_OFF);

    // ---- attention pre-phase: one pass over X for this block's 16 batches ----
    {
        const float* weff = (const float*)(ws + WEFF_OFF);
        const float4 we4 = ((const float4*)weff)[lane];
        const float4 wc4 = ((const float4*)W_fc)[lane];
        const float4 wf4 = ((const float4*)(W_final + 256))[lane];
        for (int bb = 0; bb < 16; ++bb) {
            const float* Xb = X + (size_t)(gi * 16 + bb) * T1 * ENC;
            #pragma unroll 4
            for (int ti = 0; ti < 32; ++ti) {
                const int t = w * 32 + ti;
                if (t < T1) {
                    float4 x4 = ((const float4*)(Xb + t * ENC))[lane];
                    float as = x4.x * we4.x + x4.y * we4.y + x4.z * we4.z + x4.w * we4.w;
                    float aw = x4.x * wc4.x + x4.y * wc4.y + x4.z * wc4.z + x4.w * wc4.w;
                    float af = x4.x * wf4.x + x4.y * wf4.y + x4.z * wf4.z + x4.w * wf4.w;
                    for (int m = 32; m >= 1; m >>= 1) {
                        as += __shfl_xor(as, m, 64);
                        aw += __shfl_xor(aw, m, 64);
                        af += __shfl_xor(af, m, 64);
                    }
                    if (lane == 0) {
                        s_sc[bb * 128 + t] = as;
                        s_xw[bb * 128 + t] = aw;
                        s_xf[bb * 128 + t] = af;
                    }
                }
            }
        }
        __syncthreads();
        // softmax + u/cf per batch: wave w handles batches w, w+4, w+8, w+12
        for (int ii = 0; ii < 4; ++ii) {
            const int bb = w + ii * 4;
            const bool ok1 = (lane + 64 < T1);
            float v0 = s_sc[bb * 128 + lane];
            float v1 = ok1 ? s_sc[bb * 128 + lane + 64] : -1e30f;
            float mx = fmaxf(v0, v1);
            for (int m = 32; m >= 1; m >>= 1) mx = fmaxf(mx, __shfl_xor(mx, m, 64));
            float e0 = __expf(v0 - mx);
            float e1 = ok1 ? __expf(v1 - mx) : 0.f;
            float s  = e0 + e1;
            float uw = e0 * s_xw[bb * 128 + lane] + (ok1 ? e1 * s_xw[bb * 128 + lane + 64] : 0.f);
            float uf = e0 * s_xf[bb * 128 + lane] + (ok1 ? e1 * s_xf[bb * 128 + lane + 64] : 0.f);
            for (int m = 32; m >= 1; m >>= 1) {
                s  += __shfl_xor(s, m, 64);
                uw += __shfl_xor(uw, m, 64);
                uf += __shfl_xor(uf, m, 64);
            }
            if (lane == 0) {
                const float inv = 1.f / s;
                s_u[bb] = uw * inv + b_fc[0];
                if (hj == 0) cf[gi * 16 + bb] = uf * inv;
            }
        }
        __syncthreads();
    }

    // ---- resident W fragments: load W_hh directly, split hi/lo inline ----
    short8 bfh[2][8], bfl[2][8];
    #pragma unroll
    for (int j = 0; j < 2; ++j) {
        const int r = (2 * w + j) * 16 + n16;          // 0..127
        const int hloc = r >> 2, g = r & 3;
        const int R = g * 256 + hj * 32 + hloc;        // global gate row
        #pragma unroll
        for (int kt = 0; kt < 8; ++kt) {
            const float* src = W_hh + R * 256 + kt * 32 + q * 8;
            float4 f0 = ((const float4*)src)[0];
            float4 f1 = ((const float4*)src)[1];
            float vv[8] = {f0.x, f0.y, f0.z, f0.w, f1.x, f1.y, f1.z, f1.w};
            unsigned h[8], l[8];
            #pragma unroll
            for (int i = 0; i < 8; ++i) split_bf16(vv[i], h[i], l[i]);
            short8 sh, sl;
            #pragma unroll
            for (int i = 0; i < 8; ++i) { sh[i] = (short)h[i]; sl[i] = (short)l[i]; }
            bfh[j][kt] = sh;
            bfl[j][kt] = sl;
        }
    }

    // cell assignment: 16 batches x 32 h = 512 cells, 2 per thread
    const int b_loc = tid & 15, hpair = tid >> 4;      // hpair 0..15
    const int hloc0 = hpair * 2;
    const int bg = gi * 16 + b_loc;
    float wihr[2][4], bihr[2][4];
    #pragma unroll
    for (int jj = 0; jj < 2; ++jj)
        #pragma unroll
        for (int g = 0; g < 4; ++g) {
            const int row = g * HD + hj * 32 + hloc0 + jj;
            wihr[jj][g] = W_ih[row];
            bihr[jj][g] = b_ih[row] + b_hh[row];
        }
    float cc0 = 0.f, cc1 = 0.f;
    const float u_reg = s_u[b_loc];
    const float wy = W_fc[256];
    const float* ypb = y_prev + (size_t)bg * T1;

    // poll/stage assignment: thread covers batch pb = tid>>4, hp8 = tid&15
    const int pb = tid >> 4, hp8 = tid & 15;
    const bool own = ((hp8 >> 1) == hj);
    const size_t pbase = (size_t)(gi * 16 + pb) * 128 + hp8 * 8;   // 64B-aligned line

    // pre-zero this thread's full 16-ushort slab segment (d0 = 0) in BOTH planes
    {
        ushort8_t z = {0, 0, 0, 0, 0, 0, 0, 0};
        *(ushort8_t*)(ldh + pb * 264 + hp8 * 16)     = z;
        *(ushort8_t*)(ldh + pb * 264 + hp8 * 16 + 8) = z;
        *(ushort8_t*)(ldl + pb * 264 + hp8 * 16)     = z;
        *(ushort8_t*)(ldl + pb * 264 + hp8 * 16 + 8) = z;
    }

    for (int t = 1; t <= T1; ++t) {
        const float ytv = u_reg + wy * ypb[t - 1];   // prefetch, independent of d
        // ---- poll d_{t-1}: one 64-B line sample per round ----
        if (!own) {
            unsigned long long* Dsrc = ((t - 1) & 1) ? Dbuf1 : Dbuf0;
            const unsigned e = (unsigned)(t - 1) & 3u;
            unsigned lo[8], hi[8];
            for (int round = 0; ; ++round) {
                uint4 A, B, C, D;
                load64_ag(&Dsrc[pbase], A, B, C, D);
                lo[0] = A.x; hi[0] = A.y; lo[1] = A.z; hi[1] = A.w;
                lo[2] = B.x; hi[2] = B.y; lo[3] = B.z; hi[3] = B.w;
                lo[4] = C.x; hi[4] = C.y; lo[5] = C.z; hi[5] = C.w;
                lo[6] = D.x; hi[6] = D.y; lo[7] = D.z; hi[7] = D.w;
                bool ok = true;
                #pragma unroll
                for (int i = 0; i < 8; ++i) {
                    unsigned ep = (lo[i] & 1u) | ((hi[i] & 1u) << 1);
                    ok &= (ep == e);
                }
                if (ok) break;
                if (round >= 16) __builtin_amdgcn_s_sleep(1);
            }
            // decode: 16 hi + 16 lo ushorts -> two b128 stores per plane
            ushort hv[16], lv[16];
            #pragma unroll
            for (int i = 0; i < 8; ++i) {
                hv[2 * i]     = (ushort)(lo[i] >> 16);
                hv[2 * i + 1] = (ushort)(hi[i] >> 16);
                lv[2 * i]     = (ushort)(lo[i] & 0xFFFEu);
                lv[2 * i + 1] = (ushort)(hi[i] & 0xFFFEu);
            }
            ushort8_t H0, L0, H1, L1;
            #pragma unroll
            for (int i = 0; i < 8; ++i) { H0[i] = hv[i]; L0[i] = lv[i]; H1[i] = hv[8 + i]; L1[i] = lv[8 + i]; }
            *(ushort8_t*)(ldh + pb * 264 + hp8 * 16)     = H0;
            *(ushort8_t*)(ldh + pb * 264 + hp8 * 16 + 8) = H1;
            *(ushort8_t*)(ldl + pb * 264 + hp8 * 16)     = L0;
            *(ushort8_t*)(ldl + pb * 264 + hp8 * 16 + 8) = L1;
        }
        __syncthreads();
        // MFMA: gates[16b x 128r] = d[16x256] @ Wslice^T  (hi*hi + lo*hi + hi*lo)
        floatx4 acc0 = {0.f, 0.f, 0.f, 0.f}, acc1 = {0.f, 0.f, 0.f, 0.f};
        #pragma unroll
        for (int kt = 0; kt < 8; ++kt) {
            short8 ah = *(const short8*)(ldh + n16 * 264 + kt * 32 + q * 8);
            short8 al = *(const short8*)(ldl + n16 * 264 + kt * 32 + q * 8);
            acc0 = __builtin_amdgcn_mfma_f32_16x16x32_bf16(ah, bfh[0][kt], acc0, 0, 0, 0);
            acc0 = __builtin_amdgcn_mfma_f32_16x16x32_bf16(al, bfh[0][kt], acc0, 0, 0, 0);
            acc0 = __builtin_amdgcn_mfma_f32_16x16x32_bf16(ah, bfl[0][kt], acc0, 0, 0, 0);
            acc1 = __builtin_amdgcn_mfma_f32_16x16x32_bf16(ah, bfh[1][kt], acc1, 0, 0, 0);
            acc1 = __builtin_amdgcn_mfma_f32_16x16x32_bf16(al, bfh[1][kt], acc1, 0, 0, 0);
            acc1 = __builtin_amdgcn_mfma_f32_16x16x32_bf16(ah, bfl[1][kt], acc1, 0, 0, 0);
        }
        // scatter C-frags: row m = q*4+reg (batch), col = tile*16+n16 (gate row)
        #pragma unroll
        for (int reg = 0; reg < 4; ++reg) {
            gbuf[(q * 4 + reg) * 132 + (2 * w) * 16 + n16]     = acc0[reg];
            gbuf[(q * 4 + reg) * 132 + (2 * w + 1) * 16 + n16] = acc1[reg];
        }
        __syncthreads();
        // LSTM cell: 2 cells per thread
        float dnew[2];
        #pragma unroll
        for (int jj = 0; jj < 2; ++jj) {
            const int base = b_loc * 132 + (hloc0 + jj) * 4;
            float pi = gbuf[base + 0] + ytv * wihr[jj][0] + bihr[jj][0];
            float pf = gbuf[base + 1] + ytv * wihr[jj][1] + bihr[jj][1];
            float pg = gbuf[base + 2] + ytv * wihr[jj][2] + bihr[jj][2];
            float po = gbuf[base + 3] + ytv * wihr[jj][3] + bihr[jj][3];
            float ig = sigm_f(pi), fg = sigm_f(pf), og = sigm_f(po);
            float gg = tanh_f(pg);
            float& c = jj ? cc1 : cc0;
            c = fg * c + ig * gg;
            dnew[jj] = og * tanh_f(c);
        }
        if (t < T1) {
            const unsigned e = (unsigned)t & 3u;
            unsigned h0, l0, h1, l1;
            split_bf16(dnew[0], h0, l0);
            split_bf16(dnew[1], h1, l1);
            l0 = (l0 & 0xFFFEu) | (e & 1u);
            l1 = (l1 & 0xFFFEu) | ((e >> 1) & 1u);
            // publish FIRST (earliest visibility for the 7 consumer blocks)
            unsigned long long wv = ((unsigned long long)h1 << 48) |
                                    ((unsigned long long)l1 << 32) |
                                    ((unsigned long long)h0 << 16) |
                                    (unsigned long long)l0;
            unsigned long long* Ddst = (t & 1) ? Dbuf1 : Dbuf0;
            __hip_atomic_store(&Ddst[(size_t)bg * 128 + hj * 16 + hpair], wv,
                               __ATOMIC_RELAXED, __HIP_MEMORY_SCOPE_AGENT);
            // own slice -> directly into next step's LDS slab (barrier-ordered)
            *(ushort2*)(ldh + b_loc * 264 + hj * 32 + hloc0) =
                make_ushort2((ushort)h0, (ushort)h1);
            *(ushort2*)(ldl + b_loc * 264 + hj * 32 + hloc0) =
                make_ushort2((ushort)(l0 & 0xFFFEu), (ushort)(l1 & 0xFFFEu));
        } else {
            *(float2*)(dT + bg * 256 + hj * 32 + hloc0) = make_float2(dnew[0], dnew[1]);
        }
    }
}

// ---------------- k_final: y_pred = W_final[0:256]·dT + cf + b ----------------
__global__ __launch_bounds__(256) void k_final(const float* __restrict__ W_final,
                                               const float* __restrict__ b_final,
                                               float* __restrict__ out,
                                               char* __restrict__ ws) {
    __shared__ float red[256];
    const int b = blockIdx.x, tid = threadIdx.x;
    const float* dT = (const float*)(ws + DT_OFF);
    const float* cf = (const float*)(ws + CF_OFF);
    red[tid] = W_final[tid] * dT[b * 256 + tid];
    __syncthreads();
    for (int s = 128; s >= 1; s >>= 1) { if (tid < s) red[tid] += red[tid + s]; __syncthreads(); }
    if (tid == 0) out[b] = red[0] + cf[b] + b_final[0];
}

extern "C" void kernel_launch(void* const* d_in, const int* in_sizes, int n_in,
                              void* d_out, int out_size, void* d_ws, size_t ws_size,
                              hipStream_t stream) {
    const float* X      = (const float*)d_in[0];
    const float* y_prev = (const float*)d_in[1];
    const float* W1     = (const float*)d_in[2];
    const float* W2     = (const float*)d_in[4];
    const float* W_fc   = (const float*)d_in[6];
    const float* b_fc   = (const float*)d_in[7];
    const float* W_ih   = (const float*)d_in[8];
    const float* W_hh   = (const float*)d_in[9];
    const float* b_ih   = (const float*)d_in[10];
    const float* b_hh   = (const float*)d_in[11];
    const float* W_fin  = (const float*)d_in[12];
    const float* b_fin  = (const float*)d_in[13];
    char* ws = (char*)d_ws;

    hipLaunchKernelGGL(k_prep,  dim3(128), dim3(256), 0, stream, W1, W2, ws);
    hipLaunchKernelGGL(k_lstm,  dim3(256), dim3(256), 0, stream,
                       W_ih, b_ih, b_hh, W_hh, X, y_prev, W_fc, b_fc, W_fin, ws);
    hipLaunchKernelGGL(k_final, dim3(512), dim3(256), 0, stream, W_fin, b_fin, (float*)d_out, ws);
}